// Round 7
// baseline (2667.516 us; speedup 1.0000x reference)
//
#include <hip/hip_runtime.h>
#include <math.h>

#define N_NODES 50000
#define N_EDGES 600000
#define IN_DIM 64
#define DMODEL 128
#define N_LAYERS 8
#define N_ETYPES 44
#define N_MENTIONS 100000
#define N_VARS 20000
#define OUT_DIM 100

#define EPI_BIAS 0
#define EPI_BIAS_RELU 1
#define EPI_DEG_GELU 2
#define EPI_NONE 3

#define SCL  6.103515625e-05f   /* 2^-14: pre-scale into f16 range (|h| can reach ~1e7) */
#define SCLI 16384.0f

#define CCH 16                  /* channels per edge_agg pass: 50000*16*4B = 3.2MB < 4MB L2/XCD */
#define NPASS (256 / CCH)       /* 16 */

typedef _Float16 f16x8 __attribute__((ext_vector_type(8)));
typedef _Float16 f16x4 __attribute__((ext_vector_type(4)));
typedef float f32x4 __attribute__((ext_vector_type(4)));

__device__ __forceinline__ float gelu_exact(float x) {
    return 0.5f * x * (1.0f + erff(x * 0.70710678118654752f));
}

// ---------------- weight prep: transpose [K,N]->[Npad,K] and split fp32 -> f16 hi+lo ----------
__global__ void wprep(const float* __restrict__ src, _Float16* __restrict__ dhi,
                      _Float16* __restrict__ dlo, int K, int Nsrc, int Npad,
                      long srcLS, long dstLS, int cat) {
    __shared__ float sh[16][17];
    int z = blockIdx.z;
    src += (size_t)z * srcLS;
    dhi += (size_t)z * dstLS;
    dlo += (size_t)z * dstLS;
    int n0 = blockIdx.x * 16, k0 = blockIdx.y * 16;
    int tx = threadIdx.x, ty = threadIdx.y;
    int nr = n0 + tx, kr = k0 + ty;
    float v;
    if (cat) {
        int half = nr >> 8;
        int nc = nr & 255;
        v = src[(size_t)(kr + half * 128) * 256 + nc];
    } else {
        v = (nr < Nsrc) ? src[(size_t)kr * Nsrc + nr] : 0.f;
    }
    sh[ty][tx] = v;
    __syncthreads();
    float x = sh[tx][ty];
    int n = n0 + ty, k = k0 + tx;
    _Float16 hi = (_Float16)x;
    float lo = x - (float)hi;
    dhi[(size_t)n * K + k] = hi;
    dlo[(size_t)n * K + k] = (_Float16)lo;
}

// ---------------- 3xF16 MFMA GEMM ----------------
template<int EPI, int ASPLIT, int OSPLIT>
__global__ __launch_bounds__(256) void gemm3h(
        const float* __restrict__ A, const _Float16* __restrict__ Ahi,
        const _Float16* __restrict__ Alo,
        const _Float16* __restrict__ Bh, const _Float16* __restrict__ Bl,
        const float* __restrict__ bias, const int* __restrict__ deg,
        float* __restrict__ C, _Float16* __restrict__ Chi, _Float16* __restrict__ Clo,
        int M, int N, int K, int ldC) {
    __shared__ _Float16 Ah[64 * 56], Al[64 * 56], Bsh[64 * 56], Bsl[64 * 56];
    int t = threadIdx.x;
    int m0 = blockIdx.y * 64, n0 = blockIdx.x * 64;
    int ar = t >> 2, ac = (t & 3) * 8;
    int btt = t & 127, br = btt >> 1, bc = (btt & 1) * 16;
    const _Float16* Bsrc = (t < 128) ? Bh : Bl;
    _Float16* Bdst = (t < 128) ? Bsh : Bsl;
    int lane = t & 63, wid = t >> 6;
    int wm = (wid >> 1) * 32, wn = (wid & 1) * 32;
    int quad = lane >> 4, l15 = lane & 15;
    f32x4 acc[2][2] = {};
    bool arow_ok = (m0 + ar) < M;
    const float* Aptr = ASPLIT ? nullptr : (A + (size_t)(m0 + ar) * K + ac);
    const _Float16* Ahp = ASPLIT ? (Ahi + (size_t)(m0 + ar) * K + ac) : nullptr;
    const _Float16* Alp = ASPLIT ? (Alo + (size_t)(m0 + ar) * K + ac) : nullptr;
    const _Float16* Bptr = Bsrc + (size_t)(n0 + br) * K + bc;

    for (int k0 = 0; k0 < K; k0 += 32) {
        f16x8 hv = {}, lv = {};
        if (ASPLIT) {
            if (arow_ok) {
                hv = *(const f16x8*)(Ahp + k0);
                lv = *(const f16x8*)(Alp + k0);
            }
        } else {
            float4 v0 = {0, 0, 0, 0}, v1 = {0, 0, 0, 0};
            if (arow_ok) {
                v0 = *(const float4*)(Aptr + k0);
                v1 = *(const float4*)(Aptr + k0 + 4);
            }
            float xs[8] = {v0.x, v0.y, v0.z, v0.w, v1.x, v1.y, v1.z, v1.w};
#pragma unroll
            for (int j = 0; j < 8; j++) {
                float s = xs[j] * SCL;
                _Float16 h = (_Float16)s;
                hv[j] = h;
                lv[j] = (_Float16)(s - (float)h);
            }
        }
        *(f16x8*)&Ah[ar * 56 + ac] = hv;
        *(f16x8*)&Al[ar * 56 + ac] = lv;
        f16x8 b0 = *(const f16x8*)(Bptr + k0);
        f16x8 b1v = *(const f16x8*)(Bptr + k0 + 8);
        *(f16x8*)&Bdst[br * 56 + bc] = b0;
        *(f16x8*)&Bdst[br * 56 + bc + 8] = b1v;
        __syncthreads();

        f16x8 afh[2], afl[2], bfh[2], bfl[2];
#pragma unroll
        for (int i = 0; i < 2; i++) {
            int am = (wm + i * 16 + l15) * 56 + quad * 8;
            afh[i] = *(const f16x8*)&Ah[am];
            afl[i] = *(const f16x8*)&Al[am];
            int bn = (wn + i * 16 + l15) * 56 + quad * 8;
            bfh[i] = *(const f16x8*)&Bsh[bn];
            bfl[i] = *(const f16x8*)&Bsl[bn];
        }
#pragma unroll
        for (int i = 0; i < 2; i++)
#pragma unroll
            for (int j = 0; j < 2; j++) {
                acc[i][j] = __builtin_amdgcn_mfma_f32_16x16x32_f16(afh[i], bfh[j], acc[i][j], 0, 0, 0);
                acc[i][j] = __builtin_amdgcn_mfma_f32_16x16x32_f16(afh[i], bfl[j], acc[i][j], 0, 0, 0);
                acc[i][j] = __builtin_amdgcn_mfma_f32_16x16x32_f16(afl[i], bfh[j], acc[i][j], 0, 0, 0);
            }
        __syncthreads();
    }

#pragma unroll
    for (int i = 0; i < 2; i++) {
        int rowb = m0 + wm + i * 16 + quad * 4;
#pragma unroll
        for (int j = 0; j < 2; j++) {
            int col = n0 + wn + j * 16 + l15;
            if (col >= N) continue;
#pragma unroll
            for (int r = 0; r < 4; r++) {
                int row = rowb + r;
                if (row >= M) continue;
                float v = acc[i][j][r] * SCLI;
                if (EPI == EPI_BIAS) { v += bias[col]; }
                else if (EPI == EPI_BIAS_RELU) { v += bias[col]; v = fmaxf(v, 0.f); }
                else if (EPI == EPI_DEG_GELU) { v += (float)deg[row] * bias[col]; v = gelu_exact(v); }
                size_t idx = (size_t)row * ldC + col;
                if (OSPLIT) {
                    float s = v * SCL;
                    _Float16 h = (_Float16)s;
                    Chi[idx] = h;
                    Clo[idx] = (_Float16)(s - (float)h);
                } else {
                    C[idx] = v;
                }
            }
        }
    }
}

// ---------------- CSR build ----------------
__global__ void count_deg(const int* __restrict__ dst, int* __restrict__ deg) {
    int e = blockIdx.x * blockDim.x + threadIdx.x;
    if (e < N_EDGES) atomicAdd(&deg[dst[e]], 1);
}

#define SCAN_B 1024
#define SCAN_NB ((N_NODES + SCAN_B - 1) / SCAN_B)

__global__ void scan_local(const int* __restrict__ deg, int* __restrict__ offs,
                           int* __restrict__ bsum, int n) {
    __shared__ int sh[SCAN_B];
    int t = threadIdx.x;
    int i = blockIdx.x * SCAN_B + t;
    int v = (i < n) ? deg[i] : 0;
    sh[t] = v;
    __syncthreads();
    for (int o = 1; o < SCAN_B; o <<= 1) {
        int u = (t >= o) ? sh[t - o] : 0;
        __syncthreads();
        sh[t] += u;
        __syncthreads();
    }
    if (i < n) offs[i] = sh[t] - v;
    if (t == SCAN_B - 1) bsum[blockIdx.x] = sh[t];
}

__global__ void scan_block(int* __restrict__ bsum, int nb) {
    __shared__ int sh[64];
    int t = threadIdx.x;
    int v = (t < nb) ? bsum[t] : 0;
    sh[t] = v;
    __syncthreads();
    for (int o = 1; o < 64; o <<= 1) {
        int u = (t >= o) ? sh[t - o] : 0;
        __syncthreads();
        sh[t] += u;
        __syncthreads();
    }
    if (t < nb) bsum[t] = sh[t] - v;
}

__global__ void scan_final(int* __restrict__ offs, const int* __restrict__ bsum,
                           int* __restrict__ cursor, int n, int total) {
    int i = blockIdx.x * SCAN_B + threadIdx.x;
    if (i < n) {
        int o = offs[i] + bsum[blockIdx.x];
        offs[i] = o;
        cursor[i] = o;
    }
    if (i == n) offs[n] = total;
}

__global__ void place_edges(const int* __restrict__ src, const int* __restrict__ dst,
                            const int* __restrict__ lab, int* __restrict__ cursor,
                            int* __restrict__ src_s, int* __restrict__ lab_s) {
    int e = blockIdx.x * blockDim.x + threadIdx.x;
    if (e < N_EDGES) {
        int pos = atomicAdd(&cursor[dst[e]], 1);
        src_s[pos] = src[e];
        lab_s[pos] = lab[e];
    }
}

// ---------------- per-etype projection, all layers in one dispatch ----------------
__global__ void etype_proj_all(const float* __restrict__ edge_emb, const float* __restrict__ mlp_W1,
                               const float* __restrict__ mlp_b1, float* __restrict__ etp_all) {
    int et = blockIdx.x;   // 0..43
    int l  = blockIdx.y;   // 0..7
    int c = threadIdx.x;   // 256
    const float* ee = edge_emb + (size_t)l * N_ETYPES * DMODEL + (size_t)et * DMODEL;
    const float* W  = mlp_W1 + (size_t)l * 384 * 256 + (size_t)256 * 256;
    float s = mlp_b1[(size_t)l * 256 + c];
    for (int k = 0; k < DMODEL; k++)
        s += ee[k] * W[(size_t)k * 256 + c];
    etp_all[((size_t)l * N_ETYPES + et) * 256 + c] = s;
}

// ---------------- edge aggregation: channel-chunked (16 ch/pass), wave-per-node ----------------
// HH [N,512] fp32: cols 0..255 = Hd, 256..511 = Hs. Pass p handles channels [p*16, p*16+16).
// Per-pass gather working set = 50000*16*4B = 3.2MB -> fits 4MB per-XCD L2.
// Wave: 16 edge-groups x 4 lanes (float4 = 16 ch); shuffle-xor reduce over edge groups.
__global__ __launch_bounds__(256) void edge_agg(
        const float* __restrict__ HH, const float* __restrict__ etp,
        const int* __restrict__ offsets, const int* __restrict__ src_s,
        const int* __restrict__ lab_s, _Float16* __restrict__ Phi,
        _Float16* __restrict__ Plo) {
    int wid = threadIdx.x >> 6, tl = threadIdx.x & 63;
    int i = blockIdx.x * 4 + wid;
    if (i >= N_NODES) return;
    int pass = blockIdx.y;
    int eg = tl >> 2;            // edge group 0..15
    int cl = tl & 3;             // channel sub-lane 0..3
    int cb = pass * CCH + cl * 4;
    float4 hd = *(const float4*)&HH[(size_t)i * 512 + cb];
    float4 acc = {0.f, 0.f, 0.f, 0.f};
    int e0 = offsets[i], e1 = offsets[i + 1];
    for (int e = e0 + eg; e < e1; e += 16) {
        int s = src_s[e], lb = lab_s[e];
        float4 hs = *(const float4*)&HH[(size_t)s * 512 + 256 + cb];
        float4 et = *(const float4*)&etp[lb * 256 + cb];
        acc.x += fmaxf(hd.x + hs.x + et.x, 0.f);
        acc.y += fmaxf(hd.y + hs.y + et.y, 0.f);
        acc.z += fmaxf(hd.z + hs.z + et.z, 0.f);
        acc.w += fmaxf(hd.w + hs.w + et.w, 0.f);
    }
    // reduce across the 16 edge groups (lanes differing in bits 2..5)
#pragma unroll
    for (int off = 4; off < 64; off <<= 1) {
        acc.x += __shfl_xor(acc.x, off, 64);
        acc.y += __shfl_xor(acc.y, off, 64);
        acc.z += __shfl_xor(acc.z, off, 64);
        acc.w += __shfl_xor(acc.w, off, 64);
    }
    if (eg == 0) {
        float sv[4] = {acc.x, acc.y, acc.z, acc.w};
        f16x4 ph, pl;
#pragma unroll
        for (int j = 0; j < 4; j++) {
            float s = sv[j] * SCL;
            _Float16 h = (_Float16)s;
            ph[j] = h;
            pl[j] = (_Float16)(s - (float)h);
        }
        *(f16x4*)&Phi[(size_t)i * 256 + cb] = ph;
        *(f16x4*)&Plo[(size_t)i * 256 + cb] = pl;
    }
}

// ---------------- readout ----------------
__global__ void readout_scatter(const _Float16* __restrict__ hhi, const _Float16* __restrict__ hlo,
                                const int* __restrict__ vg, const int* __restrict__ vs,
                                float* __restrict__ sums, int* __restrict__ cnt) {
    int m = blockIdx.x * 2 + (threadIdx.x >> 7);
    int c = threadIdx.x & 127;
    if (m >= N_MENTIONS) return;
    int node = vg[m];
    int v = vs[m];
    size_t idx = (size_t)node * DMODEL + c;
    float x = ((float)hhi[idx] + (float)hlo[idx]) * SCLI;
    atomicAdd(&sums[(size_t)v * DMODEL + c], x);
    if (c == 0) atomicAdd(&cnt[v], 1);
}

__global__ void divide_kernel(float* __restrict__ sums, const int* __restrict__ cnt) {
    int v = blockIdx.x;
    int c = threadIdx.x;  // 128
    float d = (float)max(cnt[v], 1);
    sums[(size_t)v * DMODEL + c] /= d;
}

// ---------------- launcher ----------------
extern "C" void kernel_launch(void* const* d_in, const int* in_sizes, int n_in,
                              void* d_out, int out_size, void* d_ws, size_t ws_size,
                              hipStream_t stream) {
    const float* node_labels = (const float*)d_in[0];
    const int*   edges       = (const int*)d_in[1];
    const int*   edge_labels = (const int*)d_in[2];
    const int*   var_gather  = (const int*)d_in[3];
    const int*   var_scatter = (const int*)d_in[4];
    const float* enc_W0 = (const float*)d_in[7];
    const float* enc_b0 = (const float*)d_in[8];
    const float* enc_W1 = (const float*)d_in[9];
    const float* enc_b1 = (const float*)d_in[10];
    const float* edge_emb = (const float*)d_in[11];
    const float* mlp_W1 = (const float*)d_in[12];
    const float* mlp_b1 = (const float*)d_in[13];
    const float* mlp_W2 = (const float*)d_in[14];
    const float* mlp_b2 = (const float*)d_in[15];
    const float* dec_W0 = (const float*)d_in[16];
    const float* dec_b0 = (const float*)d_in[17];
    const float* dec_Wl = (const float*)d_in[18];
    const float* dec_bl = (const float*)d_in[19];
    float* out = (float*)d_out;

    char* ws = (char*)d_ws;
    size_t off = 0;
    auto alloc = [&](size_t bytes) -> void* {
        void* p = ws + off;
        off += (bytes + 255) & ~(size_t)255;
        return p;
    };
    float*    HH    = (float*)alloc((size_t)N_NODES * 512 * 4);       // 102.4 MB
    _Float16* hhi   = (_Float16*)alloc((size_t)N_NODES * DMODEL * 2);
    _Float16* hlo   = (_Float16*)alloc((size_t)N_NODES * DMODEL * 2);
    _Float16* Phi   = (_Float16*)alloc((size_t)N_NODES * 256 * 2);
    _Float16* Plo   = (_Float16*)alloc((size_t)N_NODES * 256 * 2);
    float* etp_all = (float*)alloc((size_t)N_LAYERS * N_ETYPES * 256 * 4);
    int* deg    = (int*)alloc((size_t)N_NODES * 4);
    int* offs   = (int*)alloc((size_t)(N_NODES + 1) * 4);
    int* cursor = (int*)alloc((size_t)N_NODES * 4);
    int* bsum   = (int*)alloc(64 * 4);
    int* src_s  = (int*)alloc((size_t)N_EDGES * 4);
    int* lab_s  = (int*)alloc((size_t)N_EDGES * 4);
    _Float16* W1t_h = (_Float16*)alloc((size_t)N_LAYERS * 512 * 128 * 2);
    _Float16* W1t_l = (_Float16*)alloc((size_t)N_LAYERS * 512 * 128 * 2);
    _Float16* W2t_h = (_Float16*)alloc((size_t)N_LAYERS * 128 * 256 * 2);
    _Float16* W2t_l = (_Float16*)alloc((size_t)N_LAYERS * 128 * 256 * 2);
    _Float16* e0h = (_Float16*)alloc(128 * 64 * 2);
    _Float16* e0l = (_Float16*)alloc(128 * 64 * 2);
    _Float16* e1h = (_Float16*)alloc(128 * 128 * 2);
    _Float16* e1l = (_Float16*)alloc(128 * 128 * 2);
    _Float16* d0h = (_Float16*)alloc(128 * 128 * 2);
    _Float16* d0l = (_Float16*)alloc(128 * 128 * 2);
    _Float16* dlh = (_Float16*)alloc(128 * 128 * 2);
    _Float16* dll = (_Float16*)alloc(128 * 128 * 2);
    _Float16* hench = (_Float16*)alloc((size_t)N_NODES * DMODEL * 2);
    _Float16* hencl = (_Float16*)alloc((size_t)N_NODES * DMODEL * 2);
    float* vsum = (float*)alloc((size_t)N_VARS * DMODEL * 4);
    int*   vcnt = (int*)alloc((size_t)N_VARS * 4);
    _Float16* dtmph = (_Float16*)alloc((size_t)N_VARS * DMODEL * 2);
    _Float16* dtmpl = (_Float16*)alloc((size_t)N_VARS * DMODEL * 2);

    const int* e_src = edges;
    const int* e_dst = edges + N_EDGES;

    hipMemsetAsync(deg, 0, (size_t)N_NODES * 4, stream);
    hipMemsetAsync(vsum, 0, (size_t)N_VARS * DMODEL * 4, stream);
    hipMemsetAsync(vcnt, 0, (size_t)N_VARS * 4, stream);

    // CSR build (hierarchical scan)
    count_deg<<<(N_EDGES + 255) / 256, 256, 0, stream>>>(e_dst, deg);
    scan_local<<<SCAN_NB, SCAN_B, 0, stream>>>(deg, offs, bsum, N_NODES);
    scan_block<<<1, 64, 0, stream>>>(bsum, SCAN_NB);
    scan_final<<<SCAN_NB, SCAN_B, 0, stream>>>(offs, bsum, cursor, N_NODES, N_EDGES);
    place_edges<<<(N_EDGES + 255) / 256, 256, 0, stream>>>(e_src, e_dst, edge_labels, cursor,
                                                           src_s, lab_s);

    // weight prep
    dim3 pb(16, 16);
    wprep<<<dim3(32, 8, N_LAYERS), pb, 0, stream>>>(mlp_W1, W1t_h, W1t_l, 128, 512, 512,
                                                    (long)384 * 256, (long)512 * 128, 1);
    wprep<<<dim3(8, 16, N_LAYERS), pb, 0, stream>>>(mlp_W2, W2t_h, W2t_l, 256, 128, 128,
                                                    (long)256 * 128, (long)128 * 256, 0);
    wprep<<<dim3(8, 4, 1), pb, 0, stream>>>(enc_W0, e0h, e0l, 64, 128, 128, 0, 0, 0);
    wprep<<<dim3(8, 8, 1), pb, 0, stream>>>(enc_W1, e1h, e1l, 128, 128, 128, 0, 0, 0);
    wprep<<<dim3(8, 8, 1), pb, 0, stream>>>(dec_W0, d0h, d0l, 128, 128, 128, 0, 0, 0);
    wprep<<<dim3(8, 8, 1), pb, 0, stream>>>(dec_Wl, dlh, dll, 128, 100, 128, 0, 0, 0);

    // all-layer etype projections, one dispatch
    etype_proj_all<<<dim3(N_ETYPES, N_LAYERS), 256, 0, stream>>>(edge_emb, mlp_W1, mlp_b1, etp_all);

    dim3 blk(256);
    const int MT_N = (N_NODES + 63) / 64;   // 782
    const int MT_V = (N_VARS + 63) / 64;    // 313

    // encoder
    gemm3h<EPI_BIAS_RELU, 0, 1><<<dim3(2, MT_N), blk, 0, stream>>>(
        node_labels, nullptr, nullptr, e0h, e0l, enc_b0, nullptr,
        nullptr, hench, hencl, N_NODES, 128, 64, 128);
    gemm3h<EPI_BIAS, 1, 1><<<dim3(2, MT_N), blk, 0, stream>>>(
        nullptr, hench, hencl, e1h, e1l, enc_b1, nullptr,
        nullptr, hhi, hlo, N_NODES, 128, 128, 128);

    // message-passing layers
    for (int l = 0; l < N_LAYERS; ++l) {
        const float* b2 = mlp_b2 + (size_t)l * DMODEL;
        gemm3h<EPI_NONE, 1, 0><<<dim3(8, MT_N), blk, 0, stream>>>(
            nullptr, hhi, hlo, W1t_h + (size_t)l * 512 * 128, W1t_l + (size_t)l * 512 * 128,
            nullptr, nullptr, HH, nullptr, nullptr, N_NODES, 512, 128, 512);
        edge_agg<<<dim3((N_NODES + 3) / 4, NPASS), blk, 0, stream>>>(
            HH, etp_all + (size_t)l * N_ETYPES * 256, offs, src_s, lab_s, Phi, Plo);
        gemm3h<EPI_DEG_GELU, 1, 1><<<dim3(2, MT_N), blk, 0, stream>>>(
            nullptr, Phi, Plo, W2t_h + (size_t)l * 128 * 256, W2t_l + (size_t)l * 128 * 256,
            b2, deg, nullptr, hhi, hlo, N_NODES, 128, 256, 128);
    }

    // readout: scatter-mean into variables
    readout_scatter<<<(N_MENTIONS + 1) / 2, 256, 0, stream>>>(hhi, hlo, var_gather, var_scatter,
                                                              vsum, vcnt);
    divide_kernel<<<N_VARS, DMODEL, 0, stream>>>(vsum, vcnt);

    // decoder
    gemm3h<EPI_BIAS_RELU, 0, 1><<<dim3(2, MT_V), blk, 0, stream>>>(
        vsum, nullptr, nullptr, d0h, d0l, dec_b0, nullptr,
        nullptr, dtmph, dtmpl, N_VARS, 128, 128, 128);
    gemm3h<EPI_BIAS, 1, 0><<<dim3(2, MT_V), blk, 0, stream>>>(
        nullptr, dtmph, dtmpl, dlh, dll, dec_bl, nullptr,
        out, nullptr, nullptr, N_VARS, OUT_DIM, 128, OUT_DIM);
}

// Round 8
// 1735.714 us; speedup vs baseline: 1.5368x; 1.5368x over previous
//
#include <hip/hip_runtime.h>
#include <math.h>

#define N_NODES 50000
#define N_EDGES 600000
#define IN_DIM 64
#define DMODEL 128
#define N_LAYERS 8
#define N_ETYPES 44
#define N_MENTIONS 100000
#define N_VARS 20000
#define OUT_DIM 100

#define EPI_BIAS 0
#define EPI_BIAS_RELU 1
#define EPI_DEG_GELU 2
#define EPI_NONE 3

#define SCL  6.103515625e-05f   /* 2^-14: pre-scale into f16 range (|h| can reach ~1e7) */
#define SCLI 16384.0f

typedef _Float16 f16x8 __attribute__((ext_vector_type(8)));
typedef _Float16 f16x4 __attribute__((ext_vector_type(4)));
typedef float f32x4 __attribute__((ext_vector_type(4)));

__device__ __forceinline__ float gelu_exact(float x) {
    return 0.5f * x * (1.0f + erff(x * 0.70710678118654752f));
}

// ---------------- weight prep: transpose [K,N]->[Npad,K] and split fp32 -> f16 hi+lo ----------
__global__ void wprep(const float* __restrict__ src, _Float16* __restrict__ dhi,
                      _Float16* __restrict__ dlo, int K, int Nsrc, int Npad,
                      long srcLS, long dstLS, int cat) {
    __shared__ float sh[16][17];
    int z = blockIdx.z;
    src += (size_t)z * srcLS;
    dhi += (size_t)z * dstLS;
    dlo += (size_t)z * dstLS;
    int n0 = blockIdx.x * 16, k0 = blockIdx.y * 16;
    int tx = threadIdx.x, ty = threadIdx.y;
    int nr = n0 + tx, kr = k0 + ty;
    float v;
    if (cat) {
        int half = nr >> 8;
        int nc = nr & 255;
        v = src[(size_t)(kr + half * 128) * 256 + nc];
    } else {
        v = (nr < Nsrc) ? src[(size_t)kr * Nsrc + nr] : 0.f;
    }
    sh[ty][tx] = v;
    __syncthreads();
    float x = sh[tx][ty];
    int n = n0 + ty, k = k0 + tx;
    _Float16 hi = (_Float16)x;
    float lo = x - (float)hi;
    dhi[(size_t)n * K + k] = hi;
    dlo[(size_t)n * K + k] = (_Float16)lo;
}

// ---------------- 3xF16 MFMA GEMM, 64x64 tile (for N<=128 GEMMs) ----------------
template<int EPI, int ASPLIT, int OSPLIT>
__global__ __launch_bounds__(256) void gemm3h(
        const float* __restrict__ A, const _Float16* __restrict__ Ahi,
        const _Float16* __restrict__ Alo,
        const _Float16* __restrict__ Bh, const _Float16* __restrict__ Bl,
        const float* __restrict__ bias, const int* __restrict__ deg,
        float* __restrict__ C, _Float16* __restrict__ Chi, _Float16* __restrict__ Clo,
        int M, int N, int K, int ldC) {
    __shared__ _Float16 Ah[64 * 56], Al[64 * 56], Bsh[64 * 56], Bsl[64 * 56];
    int t = threadIdx.x;
    int m0 = blockIdx.y * 64, n0 = blockIdx.x * 64;
    int ar = t >> 2, ac = (t & 3) * 8;
    int btt = t & 127, br = btt >> 1, bc = (btt & 1) * 16;
    const _Float16* Bsrc = (t < 128) ? Bh : Bl;
    _Float16* Bdst = (t < 128) ? Bsh : Bsl;
    int lane = t & 63, wid = t >> 6;
    int wm = (wid >> 1) * 32, wn = (wid & 1) * 32;
    int quad = lane >> 4, l15 = lane & 15;
    f32x4 acc[2][2] = {};
    bool arow_ok = (m0 + ar) < M;
    const float* Aptr = ASPLIT ? nullptr : (A + (size_t)(m0 + ar) * K + ac);
    const _Float16* Ahp = ASPLIT ? (Ahi + (size_t)(m0 + ar) * K + ac) : nullptr;
    const _Float16* Alp = ASPLIT ? (Alo + (size_t)(m0 + ar) * K + ac) : nullptr;
    const _Float16* Bptr = Bsrc + (size_t)(n0 + br) * K + bc;

    for (int k0 = 0; k0 < K; k0 += 32) {
        f16x8 hv = {}, lv = {};
        if (ASPLIT) {
            if (arow_ok) {
                hv = *(const f16x8*)(Ahp + k0);
                lv = *(const f16x8*)(Alp + k0);
            }
        } else {
            float4 v0 = {0, 0, 0, 0}, v1 = {0, 0, 0, 0};
            if (arow_ok) {
                v0 = *(const float4*)(Aptr + k0);
                v1 = *(const float4*)(Aptr + k0 + 4);
            }
            float xs[8] = {v0.x, v0.y, v0.z, v0.w, v1.x, v1.y, v1.z, v1.w};
#pragma unroll
            for (int j = 0; j < 8; j++) {
                float s = xs[j] * SCL;
                _Float16 h = (_Float16)s;
                hv[j] = h;
                lv[j] = (_Float16)(s - (float)h);
            }
        }
        *(f16x8*)&Ah[ar * 56 + ac] = hv;
        *(f16x8*)&Al[ar * 56 + ac] = lv;
        f16x8 b0 = *(const f16x8*)(Bptr + k0);
        f16x8 b1v = *(const f16x8*)(Bptr + k0 + 8);
        *(f16x8*)&Bdst[br * 56 + bc] = b0;
        *(f16x8*)&Bdst[br * 56 + bc + 8] = b1v;
        __syncthreads();

        f16x8 afh[2], afl[2], bfh[2], bfl[2];
#pragma unroll
        for (int i = 0; i < 2; i++) {
            int am = (wm + i * 16 + l15) * 56 + quad * 8;
            afh[i] = *(const f16x8*)&Ah[am];
            afl[i] = *(const f16x8*)&Al[am];
            int bn = (wn + i * 16 + l15) * 56 + quad * 8;
            bfh[i] = *(const f16x8*)&Bsh[bn];
            bfl[i] = *(const f16x8*)&Bsl[bn];
        }
#pragma unroll
        for (int i = 0; i < 2; i++)
#pragma unroll
            for (int j = 0; j < 2; j++) {
                acc[i][j] = __builtin_amdgcn_mfma_f32_16x16x32_f16(afh[i], bfh[j], acc[i][j], 0, 0, 0);
                acc[i][j] = __builtin_amdgcn_mfma_f32_16x16x32_f16(afh[i], bfl[j], acc[i][j], 0, 0, 0);
                acc[i][j] = __builtin_amdgcn_mfma_f32_16x16x32_f16(afl[i], bfh[j], acc[i][j], 0, 0, 0);
            }
        __syncthreads();
    }

#pragma unroll
    for (int i = 0; i < 2; i++) {
        int rowb = m0 + wm + i * 16 + quad * 4;
#pragma unroll
        for (int j = 0; j < 2; j++) {
            int col = n0 + wn + j * 16 + l15;
            if (col >= N) continue;
#pragma unroll
            for (int r = 0; r < 4; r++) {
                int row = rowb + r;
                if (row >= M) continue;
                float v = acc[i][j][r] * SCLI;
                if (EPI == EPI_BIAS) { v += bias[col]; }
                else if (EPI == EPI_BIAS_RELU) { v += bias[col]; v = fmaxf(v, 0.f); }
                else if (EPI == EPI_DEG_GELU) { v += (float)deg[row] * bias[col]; v = gelu_exact(v); }
                size_t idx = (size_t)row * ldC + col;
                if (OSPLIT) {
                    float s = v * SCL;
                    _Float16 h = (_Float16)s;
                    Chi[idx] = h;
                    Clo[idx] = (_Float16)(s - (float)h);
                } else {
                    C[idx] = v;
                }
            }
        }
    }
}

// ---------------- 3xF16 MFMA GEMM, 128x128 tile (for the big N=512 W1 GEMM) ----------------
// A pre-split f16 hi/lo [M,K]; B pre-split [N,K]. 4 waves, each 64x64 via 4x4 16x16x32 tiles.
// LDS row stride 40 f16 (80B): bank-start period 8 over 16-row quad reads -> 2-way (free).
#define BLDS 40
__global__ __launch_bounds__(256) void gemm3h_big(
        const _Float16* __restrict__ Ahi, const _Float16* __restrict__ Alo,
        const _Float16* __restrict__ Bh, const _Float16* __restrict__ Bl,
        float* __restrict__ C, int M, int N, int K, int ldC) {
    __shared__ _Float16 Ah[128 * BLDS], Al[128 * BLDS], Bsh[128 * BLDS], Bsl[128 * BLDS];
    int t = threadIdx.x;
    int m0 = blockIdx.y * 128, n0 = blockIdx.x * 128;
    int lane = t & 63, wid = t >> 6;
    int wm = (wid >> 1) * 64, wn = (wid & 1) * 64;
    int quad = lane >> 4, l15 = lane & 15;
    f32x4 acc[4][4] = {};

    for (int k0 = 0; k0 < K; k0 += 32) {
        // stage 4 arrays x 128 rows x 32 f16; 2048 (arr,row,seg) units over 256 thr x 8 iters
#pragma unroll
        for (int it = 0; it < 8; it++) {
            int v = it * 256 + t;
            int seg = v & 3;
            int row = (v >> 2) & 127;
            int arr = v >> 9;
            f16x8 d = {};
            if (arr < 2) {
                int rg = m0 + row;
                if (rg < M) {
                    const _Float16* p = (arr == 0 ? Ahi : Alo) + (size_t)rg * K + k0 + seg * 8;
                    d = *(const f16x8*)p;
                }
            } else {
                int rg = n0 + row;
                if (rg < N) {
                    const _Float16* p = (arr == 2 ? Bh : Bl) + (size_t)rg * K + k0 + seg * 8;
                    d = *(const f16x8*)p;
                }
            }
            _Float16* dst = (arr == 0) ? Ah : (arr == 1) ? Al : (arr == 2) ? Bsh : Bsl;
            *(f16x8*)&dst[row * BLDS + seg * 8] = d;
        }
        __syncthreads();

        f16x8 afh[4], afl[4], bfh[4], bfl[4];
#pragma unroll
        for (int i = 0; i < 4; i++) {
            int am = (wm + i * 16 + l15) * BLDS + quad * 8;
            afh[i] = *(const f16x8*)&Ah[am];
            afl[i] = *(const f16x8*)&Al[am];
            int bn = (wn + i * 16 + l15) * BLDS + quad * 8;
            bfh[i] = *(const f16x8*)&Bsh[bn];
            bfl[i] = *(const f16x8*)&Bsl[bn];
        }
#pragma unroll
        for (int i = 0; i < 4; i++)
#pragma unroll
            for (int j = 0; j < 4; j++) {
                acc[i][j] = __builtin_amdgcn_mfma_f32_16x16x32_f16(afh[i], bfh[j], acc[i][j], 0, 0, 0);
                acc[i][j] = __builtin_amdgcn_mfma_f32_16x16x32_f16(afh[i], bfl[j], acc[i][j], 0, 0, 0);
                acc[i][j] = __builtin_amdgcn_mfma_f32_16x16x32_f16(afl[i], bfh[j], acc[i][j], 0, 0, 0);
            }
        __syncthreads();
    }

#pragma unroll
    for (int i = 0; i < 4; i++) {
        int rowb = m0 + wm + i * 16 + quad * 4;
#pragma unroll
        for (int j = 0; j < 4; j++) {
            int col = n0 + wn + j * 16 + l15;
            if (col >= N) continue;
#pragma unroll
            for (int r = 0; r < 4; r++) {
                int row = rowb + r;
                if (row >= M) continue;
                C[(size_t)row * ldC + col] = acc[i][j][r] * SCLI;
            }
        }
    }
}

// ---------------- CSR build ----------------
__global__ void count_deg(const int* __restrict__ dst, int* __restrict__ deg) {
    int e = blockIdx.x * blockDim.x + threadIdx.x;
    if (e < N_EDGES) atomicAdd(&deg[dst[e]], 1);
}

#define SCAN_B 1024
#define SCAN_NB ((N_NODES + SCAN_B - 1) / SCAN_B)

__global__ void scan_local(const int* __restrict__ deg, int* __restrict__ offs,
                           int* __restrict__ bsum, int n) {
    __shared__ int sh[SCAN_B];
    int t = threadIdx.x;
    int i = blockIdx.x * SCAN_B + t;
    int v = (i < n) ? deg[i] : 0;
    sh[t] = v;
    __syncthreads();
    for (int o = 1; o < SCAN_B; o <<= 1) {
        int u = (t >= o) ? sh[t - o] : 0;
        __syncthreads();
        sh[t] += u;
        __syncthreads();
    }
    if (i < n) offs[i] = sh[t] - v;
    if (t == SCAN_B - 1) bsum[blockIdx.x] = sh[t];
}

__global__ void scan_block(int* __restrict__ bsum, int nb) {
    __shared__ int sh[64];
    int t = threadIdx.x;
    int v = (t < nb) ? bsum[t] : 0;
    sh[t] = v;
    __syncthreads();
    for (int o = 1; o < 64; o <<= 1) {
        int u = (t >= o) ? sh[t - o] : 0;
        __syncthreads();
        sh[t] += u;
        __syncthreads();
    }
    if (t < nb) bsum[t] = sh[t] - v;
}

__global__ void scan_final(int* __restrict__ offs, const int* __restrict__ bsum,
                           int* __restrict__ cursor, int n, int total) {
    int i = blockIdx.x * SCAN_B + threadIdx.x;
    if (i < n) {
        int o = offs[i] + bsum[blockIdx.x];
        offs[i] = o;
        cursor[i] = o;
    }
    if (i == n) offs[n] = total;
}

__global__ void place_edges(const int* __restrict__ src, const int* __restrict__ dst,
                            const int* __restrict__ lab, int* __restrict__ cursor,
                            int* __restrict__ src_s, int* __restrict__ lab_s) {
    int e = blockIdx.x * blockDim.x + threadIdx.x;
    if (e < N_EDGES) {
        int pos = atomicAdd(&cursor[dst[e]], 1);
        src_s[pos] = src[e];
        lab_s[pos] = lab[e];
    }
}

// ---------------- per-etype projection, all layers in one dispatch ----------------
__global__ void etype_proj_all(const float* __restrict__ edge_emb, const float* __restrict__ mlp_W1,
                               const float* __restrict__ mlp_b1, float* __restrict__ etp_all) {
    int et = blockIdx.x;   // 0..43
    int l  = blockIdx.y;   // 0..7
    int c = threadIdx.x;   // 256
    const float* ee = edge_emb + (size_t)l * N_ETYPES * DMODEL + (size_t)et * DMODEL;
    const float* W  = mlp_W1 + (size_t)l * 384 * 256 + (size_t)256 * 256;
    float s = mlp_b1[(size_t)l * 256 + c];
    for (int k = 0; k < DMODEL; k++)
        s += ee[k] * W[(size_t)k * 256 + c];
    etp_all[((size_t)l * N_ETYPES + et) * 256 + c] = s;
}

// ---------------- edge aggregation: wave-per-node, unroll x4 (round-6 version) ----------------
__global__ __launch_bounds__(256) void edge_agg(
        const float* __restrict__ HH, const float* __restrict__ etp,
        const int* __restrict__ offsets, const int* __restrict__ src_s,
        const int* __restrict__ lab_s, _Float16* __restrict__ Phi,
        _Float16* __restrict__ Plo) {
    int wid = threadIdx.x >> 6, tl = threadIdx.x & 63;
    int i = blockIdx.x * 4 + wid;
    if (i >= N_NODES) return;
    int c4 = tl * 4;
    float4 hd = *(const float4*)&HH[(size_t)i * 512 + c4];
    float4 acc = {0.f, 0.f, 0.f, 0.f};
    int e0 = offsets[i], e1 = offsets[i + 1];
    int e = e0;
    for (; e + 3 < e1; e += 4) {
        int s0 = src_s[e],     l0 = lab_s[e];
        int s1 = src_s[e + 1], l1 = lab_s[e + 1];
        int s2 = src_s[e + 2], l2 = lab_s[e + 2];
        int s3 = src_s[e + 3], l3 = lab_s[e + 3];
        float4 hs0 = *(const float4*)&HH[(size_t)s0 * 512 + 256 + c4];
        float4 hs1 = *(const float4*)&HH[(size_t)s1 * 512 + 256 + c4];
        float4 hs2 = *(const float4*)&HH[(size_t)s2 * 512 + 256 + c4];
        float4 hs3 = *(const float4*)&HH[(size_t)s3 * 512 + 256 + c4];
        float4 et0 = *(const float4*)&etp[l0 * 256 + c4];
        float4 et1 = *(const float4*)&etp[l1 * 256 + c4];
        float4 et2 = *(const float4*)&etp[l2 * 256 + c4];
        float4 et3 = *(const float4*)&etp[l3 * 256 + c4];
        acc.x += fmaxf(hd.x + hs0.x + et0.x, 0.f) + fmaxf(hd.x + hs1.x + et1.x, 0.f)
               + fmaxf(hd.x + hs2.x + et2.x, 0.f) + fmaxf(hd.x + hs3.x + et3.x, 0.f);
        acc.y += fmaxf(hd.y + hs0.y + et0.y, 0.f) + fmaxf(hd.y + hs1.y + et1.y, 0.f)
               + fmaxf(hd.y + hs2.y + et2.y, 0.f) + fmaxf(hd.y + hs3.y + et3.y, 0.f);
        acc.z += fmaxf(hd.z + hs0.z + et0.z, 0.f) + fmaxf(hd.z + hs1.z + et1.z, 0.f)
               + fmaxf(hd.z + hs2.z + et2.z, 0.f) + fmaxf(hd.z + hs3.z + et3.z, 0.f);
        acc.w += fmaxf(hd.w + hs0.w + et0.w, 0.f) + fmaxf(hd.w + hs1.w + et1.w, 0.f)
               + fmaxf(hd.w + hs2.w + et2.w, 0.f) + fmaxf(hd.w + hs3.w + et3.w, 0.f);
    }
    for (; e < e1; ++e) {
        int s0 = src_s[e], l0 = lab_s[e];
        float4 hs0 = *(const float4*)&HH[(size_t)s0 * 512 + 256 + c4];
        float4 et0 = *(const float4*)&etp[l0 * 256 + c4];
        acc.x += fmaxf(hd.x + hs0.x + et0.x, 0.f);
        acc.y += fmaxf(hd.y + hs0.y + et0.y, 0.f);
        acc.z += fmaxf(hd.z + hs0.z + et0.z, 0.f);
        acc.w += fmaxf(hd.w + hs0.w + et0.w, 0.f);
    }
    float sv[4] = {acc.x, acc.y, acc.z, acc.w};
    f16x4 ph, pl;
#pragma unroll
    for (int j = 0; j < 4; j++) {
        float s = sv[j] * SCL;
        _Float16 h = (_Float16)s;
        ph[j] = h;
        pl[j] = (_Float16)(s - (float)h);
    }
    *(f16x4*)&Phi[(size_t)i * 256 + c4] = ph;
    *(f16x4*)&Plo[(size_t)i * 256 + c4] = pl;
}

// ---------------- readout ----------------
__global__ void readout_scatter(const _Float16* __restrict__ hhi, const _Float16* __restrict__ hlo,
                                const int* __restrict__ vg, const int* __restrict__ vs,
                                float* __restrict__ sums, int* __restrict__ cnt) {
    int m = blockIdx.x * 2 + (threadIdx.x >> 7);
    int c = threadIdx.x & 127;
    if (m >= N_MENTIONS) return;
    int node = vg[m];
    int v = vs[m];
    size_t idx = (size_t)node * DMODEL + c;
    float x = ((float)hhi[idx] + (float)hlo[idx]) * SCLI;
    atomicAdd(&sums[(size_t)v * DMODEL + c], x);
    if (c == 0) atomicAdd(&cnt[v], 1);
}

__global__ void divide_kernel(float* __restrict__ sums, const int* __restrict__ cnt) {
    int v = blockIdx.x;
    int c = threadIdx.x;  // 128
    float d = (float)max(cnt[v], 1);
    sums[(size_t)v * DMODEL + c] /= d;
}

// ---------------- launcher ----------------
extern "C" void kernel_launch(void* const* d_in, const int* in_sizes, int n_in,
                              void* d_out, int out_size, void* d_ws, size_t ws_size,
                              hipStream_t stream) {
    const float* node_labels = (const float*)d_in[0];
    const int*   edges       = (const int*)d_in[1];
    const int*   edge_labels = (const int*)d_in[2];
    const int*   var_gather  = (const int*)d_in[3];
    const int*   var_scatter = (const int*)d_in[4];
    const float* enc_W0 = (const float*)d_in[7];
    const float* enc_b0 = (const float*)d_in[8];
    const float* enc_W1 = (const float*)d_in[9];
    const float* enc_b1 = (const float*)d_in[10];
    const float* edge_emb = (const float*)d_in[11];
    const float* mlp_W1 = (const float*)d_in[12];
    const float* mlp_b1 = (const float*)d_in[13];
    const float* mlp_W2 = (const float*)d_in[14];
    const float* mlp_b2 = (const float*)d_in[15];
    const float* dec_W0 = (const float*)d_in[16];
    const float* dec_b0 = (const float*)d_in[17];
    const float* dec_Wl = (const float*)d_in[18];
    const float* dec_bl = (const float*)d_in[19];
    float* out = (float*)d_out;

    char* ws = (char*)d_ws;
    size_t off = 0;
    auto alloc = [&](size_t bytes) -> void* {
        void* p = ws + off;
        off += (bytes + 255) & ~(size_t)255;
        return p;
    };
    float*    HH    = (float*)alloc((size_t)N_NODES * 512 * 4);       // 102.4 MB
    _Float16* hhi   = (_Float16*)alloc((size_t)N_NODES * DMODEL * 2);
    _Float16* hlo   = (_Float16*)alloc((size_t)N_NODES * DMODEL * 2);
    _Float16* Phi   = (_Float16*)alloc((size_t)N_NODES * 256 * 2);
    _Float16* Plo   = (_Float16*)alloc((size_t)N_NODES * 256 * 2);
    float* etp_all = (float*)alloc((size_t)N_LAYERS * N_ETYPES * 256 * 4);
    int* deg    = (int*)alloc((size_t)N_NODES * 4);
    int* offs   = (int*)alloc((size_t)(N_NODES + 1) * 4);
    int* cursor = (int*)alloc((size_t)N_NODES * 4);
    int* bsum   = (int*)alloc(64 * 4);
    int* src_s  = (int*)alloc((size_t)N_EDGES * 4);
    int* lab_s  = (int*)alloc((size_t)N_EDGES * 4);
    _Float16* W1t_h = (_Float16*)alloc((size_t)N_LAYERS * 512 * 128 * 2);
    _Float16* W1t_l = (_Float16*)alloc((size_t)N_LAYERS * 512 * 128 * 2);
    _Float16* W2t_h = (_Float16*)alloc((size_t)N_LAYERS * 128 * 256 * 2);
    _Float16* W2t_l = (_Float16*)alloc((size_t)N_LAYERS * 128 * 256 * 2);
    _Float16* e0h = (_Float16*)alloc(128 * 64 * 2);
    _Float16* e0l = (_Float16*)alloc(128 * 64 * 2);
    _Float16* e1h = (_Float16*)alloc(128 * 128 * 2);
    _Float16* e1l = (_Float16*)alloc(128 * 128 * 2);
    _Float16* d0h = (_Float16*)alloc(128 * 128 * 2);
    _Float16* d0l = (_Float16*)alloc(128 * 128 * 2);
    _Float16* dlh = (_Float16*)alloc(128 * 128 * 2);
    _Float16* dll = (_Float16*)alloc(128 * 128 * 2);
    _Float16* hench = (_Float16*)alloc((size_t)N_NODES * DMODEL * 2);
    _Float16* hencl = (_Float16*)alloc((size_t)N_NODES * DMODEL * 2);
    float* vsum = (float*)alloc((size_t)N_VARS * DMODEL * 4);
    int*   vcnt = (int*)alloc((size_t)N_VARS * 4);
    _Float16* dtmph = (_Float16*)alloc((size_t)N_VARS * DMODEL * 2);
    _Float16* dtmpl = (_Float16*)alloc((size_t)N_VARS * DMODEL * 2);

    const int* e_src = edges;
    const int* e_dst = edges + N_EDGES;

    hipMemsetAsync(deg, 0, (size_t)N_NODES * 4, stream);
    hipMemsetAsync(vsum, 0, (size_t)N_VARS * DMODEL * 4, stream);
    hipMemsetAsync(vcnt, 0, (size_t)N_VARS * 4, stream);

    // CSR build (hierarchical scan)
    count_deg<<<(N_EDGES + 255) / 256, 256, 0, stream>>>(e_dst, deg);
    scan_local<<<SCAN_NB, SCAN_B, 0, stream>>>(deg, offs, bsum, N_NODES);
    scan_block<<<1, 64, 0, stream>>>(bsum, SCAN_NB);
    scan_final<<<SCAN_NB, SCAN_B, 0, stream>>>(offs, bsum, cursor, N_NODES, N_EDGES);
    place_edges<<<(N_EDGES + 255) / 256, 256, 0, stream>>>(e_src, e_dst, edge_labels, cursor,
                                                           src_s, lab_s);

    // weight prep
    dim3 pb(16, 16);
    wprep<<<dim3(32, 8, N_LAYERS), pb, 0, stream>>>(mlp_W1, W1t_h, W1t_l, 128, 512, 512,
                                                    (long)384 * 256, (long)512 * 128, 1);
    wprep<<<dim3(8, 16, N_LAYERS), pb, 0, stream>>>(mlp_W2, W2t_h, W2t_l, 256, 128, 128,
                                                    (long)256 * 128, (long)128 * 256, 0);
    wprep<<<dim3(8, 4, 1), pb, 0, stream>>>(enc_W0, e0h, e0l, 64, 128, 128, 0, 0, 0);
    wprep<<<dim3(8, 8, 1), pb, 0, stream>>>(enc_W1, e1h, e1l, 128, 128, 128, 0, 0, 0);
    wprep<<<dim3(8, 8, 1), pb, 0, stream>>>(dec_W0, d0h, d0l, 128, 128, 128, 0, 0, 0);
    wprep<<<dim3(8, 8, 1), pb, 0, stream>>>(dec_Wl, dlh, dll, 128, 100, 128, 0, 0, 0);

    // all-layer etype projections, one dispatch
    etype_proj_all<<<dim3(N_ETYPES, N_LAYERS), 256, 0, stream>>>(edge_emb, mlp_W1, mlp_b1, etp_all);

    dim3 blk(256);
    const int MT_N = (N_NODES + 63) / 64;    // 782
    const int MT_V = (N_VARS + 63) / 64;     // 313
    const int MTB_N = (N_NODES + 127) / 128; // 391

    // encoder
    gemm3h<EPI_BIAS_RELU, 0, 1><<<dim3(2, MT_N), blk, 0, stream>>>(
        node_labels, nullptr, nullptr, e0h, e0l, enc_b0, nullptr,
        nullptr, hench, hencl, N_NODES, 128, 64, 128);
    gemm3h<EPI_BIAS, 1, 1><<<dim3(2, MT_N), blk, 0, stream>>>(
        nullptr, hench, hencl, e1h, e1l, enc_b1, nullptr,
        nullptr, hhi, hlo, N_NODES, 128, 128, 128);

    // message-passing layers
    for (int l = 0; l < N_LAYERS; ++l) {
        const float* b2 = mlp_b2 + (size_t)l * DMODEL;
        gemm3h_big<<<dim3(4, MTB_N), blk, 0, stream>>>(
            hhi, hlo, W1t_h + (size_t)l * 512 * 128, W1t_l + (size_t)l * 512 * 128,
            HH, N_NODES, 512, 128, 512);
        edge_agg<<<(N_NODES + 3) / 4, blk, 0, stream>>>(
            HH, etp_all + (size_t)l * N_ETYPES * 256, offs, src_s, lab_s, Phi, Plo);
        gemm3h<EPI_DEG_GELU, 1, 1><<<dim3(2, MT_N), blk, 0, stream>>>(
            nullptr, Phi, Plo, W2t_h + (size_t)l * 128 * 256, W2t_l + (size_t)l * 128 * 256,
            b2, deg, nullptr, hhi, hlo, N_NODES, 128, 256, 128);
    }

    // readout: scatter-mean into variables
    readout_scatter<<<(N_MENTIONS + 1) / 2, 256, 0, stream>>>(hhi, hlo, var_gather, var_scatter,
                                                              vsum, vcnt);
    divide_kernel<<<N_VARS, DMODEL, 0, stream>>>(vsum, vcnt);

    // decoder
    gemm3h<EPI_BIAS_RELU, 0, 1><<<dim3(2, MT_V), blk, 0, stream>>>(
        vsum, nullptr, nullptr, d0h, d0l, dec_b0, nullptr,
        nullptr, dtmph, dtmpl, N_VARS, 128, 128, 128);
    gemm3h<EPI_BIAS, 1, 0><<<dim3(2, MT_V), blk, 0, stream>>>(
        nullptr, dtmph, dtmpl, dlh, dll, dec_bl, nullptr,
        out, nullptr, nullptr, N_VARS, OUT_DIM, 128, OUT_DIM);
}